// Round 9
// baseline (483.552 us; speedup 1.0000x reference)
//
#include <hip/hip_runtime.h>
#include <math.h>

#define NNODES 883
#define BB 8
#define DIMS_ 160
#define HID_ 320
#define PBB 944                 // padded rows per batch (patch offsets aligned to 8)
#define RMAX2 (BB*PBB)          // 7552 packed rows incl. padding
#define RMAXP (RMAX2+64)        // vt row stride
#define MAXT 16

typedef __attribute__((ext_vector_type(8))) short short8v;   // 8 bf16 in 4 VGPRs
typedef __attribute__((ext_vector_type(4))) float fx4;
typedef __attribute__((ext_vector_type(4))) unsigned short ushort4v;

__device__ __forceinline__ unsigned short f2bf(float f) {
  unsigned int u = __float_as_uint(f);
  u = (u + 0x7fffu + ((u >> 16) & 1u)) >> 16;   // RNE
  return (unsigned short)u;
}
__device__ __forceinline__ float bf2f(unsigned short u) {
  return __uint_as_float(((unsigned int)u) << 16);
}
__device__ __forceinline__ float gelu_f(float v) {
  return 0.5f*v*(1.f + erff(v*0.70710678118654752f));
}

// ---------------- patch assignment ----------------
__global__ __launch_bounds__(128)
void patch_kernel(const float* __restrict__ node_table,
                  const float* __restrict__ patch_emb,
                  float* __restrict__ probs_st,
                  float* __restrict__ nsoft,
                  int* __restrict__ patch_ids) {
  int n = blockIdx.x * blockDim.x + threadIdx.x;
  if (n >= NNODES) return;
  float nt[32];
#pragma unroll
  for (int j = 0; j < 32; ++j) nt[j] = node_table[n*32 + j];
  float lg[8];
#pragma unroll
  for (int r = 0; r < 8; ++r) {
    float a = 0.f;
#pragma unroll
    for (int j = 0; j < 32; ++j) a += nt[j] * patch_emb[r*32 + j];
    lg[r] = a;
  }
  float m = lg[0];
#pragma unroll
  for (int r = 1; r < 8; ++r) m = fmaxf(m, lg[r]);
  float e[8]; float s = 0.f;
#pragma unroll
  for (int r = 0; r < 8; ++r) { e[r] = expf(lg[r] - m); s += e[r]; }
  float p[8];
#pragma unroll
  for (int r = 0; r < 8; ++r) p[r] = e[r] / s;
  int am = 0; float best = p[0];
#pragma unroll
  for (int r = 1; r < 8; ++r) if (p[r] > best) { best = p[r]; am = r; }
  patch_ids[n] = am;
#pragma unroll
  for (int r = 0; r < 8; ++r) {
    float hard = (r == am) ? 1.f : 0.f;
    probs_st[n*8 + r] = (hard - p[r]) + p[r];
  }
#pragma unroll
  for (int j = 0; j < 32; ++j) {
    float a = 0.f;
#pragma unroll
    for (int r = 0; r < 8; ++r) a += p[r] * patch_emb[r*32 + j];
    nsoft[n*32 + j] = a;
  }
}

// ---------------- parallel scan (patch offsets aligned to 8 rows) ----------------
__global__ __launch_bounds__(1024)
void scan_kernel(const int* __restrict__ patch_ids,
                 int* __restrict__ pk, int* __restrict__ cnt,
                 int* __restrict__ offs, int* __restrict__ cntmax) {
  __shared__ int pid_s[NNODES];
  __shared__ int cnt_s[8], offs_s[8];
  int t = threadIdx.x;
  if (t < 8) cnt_s[t] = 0;
  for (int n = t; n < NNODES; n += 1024) pid_s[n] = patch_ids[n];
  __syncthreads();
  int p = -1, pos = 0;
  if (t < NNODES) {
    p = pid_s[t];
    atomicAdd(&cnt_s[p], 1);
    for (int m = 0; m < t; ++m) pos += (pid_s[m] == p) ? 1 : 0;
  }
  __syncthreads();
  if (t == 0) {
    int o = 0, mx = 0;
#pragma unroll
    for (int r = 0; r < 8; ++r) {
      offs_s[r] = o; offs[r] = o; cnt[r] = cnt_s[r];
      if (cnt_s[r] > mx) mx = cnt_s[r];
      o += (cnt_s[r] + 7) & ~7;
    }
    cntmax[0] = mx;
  }
  __syncthreads();
  if (t < NNODES) pk[t] = offs_s[p] + pos;
}

// ---------------- embedding ----------------
__global__ __launch_bounds__(160)
void embed_kernel(const float* __restrict__ x, const int* __restrict__ te,
                  const float* __restrict__ convW, const float* __restrict__ convB,
                  const float* __restrict__ tod, const float* __restrict__ dow,
                  const float* __restrict__ nsoft, const int* __restrict__ pk,
                  float* __restrict__ pf) {
  int n = blockIdx.x, b = blockIdx.y, t = threadIdx.x;
  __shared__ float xs[3][12];
  if (t < 12) {
    int l = t;
    xs[0][l] = x[(b*12 + l)*NNODES + n];
    int base = ((b*12 + l)*NNODES + n)*2;
    xs[1][l] = (float)te[base]     / 288.0f;
    xs[2][l] = (float)te[base + 1] / 7.0f;
  }
  __syncthreads();
  int row = b*PBB + pk[n];
  float val;
  if (t < 64) {
    float a = convB[t];
#pragma unroll
    for (int c = 0; c < 3; ++c)
#pragma unroll
      for (int l = 0; l < 12; ++l)
        a += xs[c][l] * convW[t*36 + c*12 + l];
    val = a;
  } else if (t < 96) {
    int ti = te[((b*12 + 11)*NNODES + n)*2 + 0];
    val = tod[ti*32 + (t - 64)];
  } else if (t < 128) {
    int dw = te[((b*12 + 11)*NNODES + n)*2 + 1];
    val = dow[dw*32 + (t - 96)];
  } else {
    val = nsoft[n*32 + (t - 128)];
  }
  pf[row*DIMS_ + t] = val;
}

// ---------------- all weight converts in one launch (transpose to bf16 [N][K]) ----------------
__global__ __launch_bounds__(256)
void cvt_all(const float* __restrict__ attn_W, const float* __restrict__ mlp_W1,
             const float* __restrict__ mlp_W2,
             unsigned short* __restrict__ wt_attn, unsigned short* __restrict__ wt_w1,
             unsigned short* __restrict__ wt_w2) {
  int y = blockIdx.y;
  const float* src; unsigned short* dst; int K, N;
  if (y < 24)      { src = attn_W + (size_t)y*25600;        dst = wt_attn + (size_t)y*25600; K = 160; N = 160; }
  else if (y < 30) { int q = y-24; src = mlp_W1 + (size_t)q*160*320; dst = wt_w1 + (size_t)q*51200; K = 160; N = 320; }
  else             { int q = y-30; src = mlp_W2 + (size_t)q*320*160; dst = wt_w2 + (size_t)q*51200; K = 320; N = 160; }
  int total = K*N;
  for (int idx = blockIdx.x*256 + threadIdx.x; idx < total; idx += gridDim.x*256) {
    int n = idx / K, k = idx - n*K;
    dst[idx] = f2bf(src[(size_t)k*N + n]);
  }
}

// ---------------- standalone LN -> bf16 xn (first block only) ----------------
__global__ __launch_bounds__(64)
void ln_xn(const float* __restrict__ pf, const float* __restrict__ g,
           const float* __restrict__ bt, unsigned short* __restrict__ xn) {
  int lane = threadIdx.x, r15 = lane & 15, kg = lane >> 4;
  int row0 = blockIdx.x * 16;
  float v[10][4];
  float s[4] = {0,0,0,0}, ss[4] = {0,0,0,0};
#pragma unroll
  for (int n = 0; n < 10; ++n) {
    int col = n*16 + r15;
#pragma unroll
    for (int i = 0; i < 4; ++i) {
      float xv = pf[(size_t)(row0 + 4*kg + i)*DIMS_ + col];
      v[n][i] = xv; s[i] += xv; ss[i] += xv*xv;
    }
  }
#pragma unroll
  for (int i = 0; i < 4; ++i) {
    s[i] += __shfl_xor(s[i], 1, 16); ss[i] += __shfl_xor(ss[i], 1, 16);
    s[i] += __shfl_xor(s[i], 2, 16); ss[i] += __shfl_xor(ss[i], 2, 16);
    s[i] += __shfl_xor(s[i], 4, 16); ss[i] += __shfl_xor(ss[i], 4, 16);
    s[i] += __shfl_xor(s[i], 8, 16); ss[i] += __shfl_xor(ss[i], 8, 16);
  }
#pragma unroll
  for (int n = 0; n < 10; ++n) {
    int col = n*16 + r15;
    float gv = g[col], bv = bt[col];
#pragma unroll
    for (int i = 0; i < 4; ++i) {
      float mu = s[i]*(1.f/160.f);
      float var = ss[i]*(1.f/160.f) - mu*mu;
      float rs = rsqrtf(var + 1e-5f);
      xn[(size_t)(row0 + 4*kg + i)*DIMS_ + col] = f2bf((v[n][i] - mu)*rs*gv + bv);
    }
  }
}

// ---------------- MFMA matmul (QKV): bf16 in, bf16 out, one wave = 16 rows x 80 cols ----------------
template<int K, bool TRANSV, int CT>
__global__ __launch_bounds__(64)
void mfma_mm(const unsigned short* __restrict__ Xv, const unsigned short* __restrict__ Wt,
             const float* __restrict__ bias, unsigned short* __restrict__ Cv,
             int M, int Cstride, size_t Wystep, size_t Cystep, int bystep) {
  constexpr int NS = K / 32;
  int lane = threadIdx.x;
  int r15  = lane & 15;
  int kg   = lane >> 4;
  int row0 = blockIdx.x * 16;
  int colbase = blockIdx.y * (CT*16);
  int z = blockIdx.z;
  Wt   += (size_t)z * Wystep;
  bias += (size_t)z * bystep;

  int ar = row0 + r15; if (ar > M-1) ar = M-1;
  short8v afrag[NS];
  const unsigned short* Xr = Xv + (size_t)ar*K + kg*8;
#pragma unroll
  for (int t = 0; t < NS; ++t)
    afrag[t] = *(const short8v*)(const void*)(Xr + t*32);

  fx4 acc[CT];
#pragma unroll
  for (int n = 0; n < CT; ++n) acc[n] = (fx4){0.f,0.f,0.f,0.f};

  const unsigned short* Wb = Wt + (size_t)(colbase + r15)*K + kg*8;
#pragma unroll
  for (int t = 0; t < NS; ++t)
#pragma unroll
    for (int n = 0; n < CT; ++n) {
      short8v bfr = *(const short8v*)(const void*)(Wb + (size_t)n*16*K + t*32);
      acc[n] = __builtin_amdgcn_mfma_f32_16x16x32_bf16(afrag[t], bfr, acc[n], 0, 0, 0);
    }

  int orow0 = row0 + kg*4;
  unsigned short* C = Cv + (size_t)z * Cystep;
#pragma unroll
  for (int n = 0; n < CT; ++n) {
    int col = colbase + n*16 + r15;
    float bv = bias[col];
#pragma unroll
    for (int i = 0; i < 4; ++i) {
      int rr = orow0 + i;
      if (rr >= M) continue;
      unsigned short h = f2bf(acc[n][i] + bv);
      if (TRANSV && z == 2) C[(size_t)col*RMAXP + rr] = h;
      else                  C[(size_t)rr*Cstride + col] = h;
    }
  }
}

// ---------------- fused proj + residual + LN + MLP1(gelu) + MLP2 + residual + LN_next ----------------
template<bool HASNEXT>
__global__ __launch_bounds__(64)
void fused_mlp(const unsigned short* __restrict__ ab,
               const unsigned short* __restrict__ wproj, const float* __restrict__ bproj,
               const unsigned short* __restrict__ w1, const float* __restrict__ b1v,
               const unsigned short* __restrict__ w2, const float* __restrict__ b2v,
               const float* __restrict__ g1, const float* __restrict__ bt1,
               const float* __restrict__ gn, const float* __restrict__ btn,
               float* __restrict__ pf, unsigned short* __restrict__ xn) {
  __shared__ unsigned short L1s[16*192];   // 16 rows x 384 B (3x128, swizzle-safe)
  __shared__ unsigned short L2s[16*320];   // 16 rows x 640 B (5x128)
  char* L1 = (char*)L1s; char* L2 = (char*)L2s;
  int lane = threadIdx.x, r15 = lane & 15, kg = lane >> 4;
  int row0 = blockIdx.x * 16;

  // ---- phase 1: proj (A = ab rows, 10 col-tiles)
  short8v af[5];
  {
    const unsigned short* Ar = ab + (size_t)(row0 + r15)*DIMS_ + kg*8;
#pragma unroll
    for (int t = 0; t < 5; ++t) af[t] = *(const short8v*)(const void*)(Ar + t*32);
  }
  fx4 acc[10];
#pragma unroll
  for (int n = 0; n < 10; ++n) acc[n] = (fx4){0.f,0.f,0.f,0.f};
#pragma unroll
  for (int t = 0; t < 5; ++t)
#pragma unroll
    for (int n = 0; n < 10; ++n) {
      short8v bfr = *(const short8v*)(const void*)(wproj + (size_t)(n*16 + r15)*160 + t*32 + kg*8);
      acc[n] = __builtin_amdgcn_mfma_f32_16x16x32_bf16(af[t], bfr, acc[n], 0, 0, 0);
    }
  // residual + store pf + LN -> L1 (swizzled bf16)
  {
    float s[4] = {0,0,0,0}, ss[4] = {0,0,0,0};
    float pn[10][4];
#pragma unroll
    for (int n = 0; n < 10; ++n) {
      int col = n*16 + r15;
      float bv = bproj[col];
#pragma unroll
      for (int i = 0; i < 4; ++i) {
        int row = row0 + 4*kg + i;
        float v = pf[(size_t)row*DIMS_ + col] + acc[n][i] + bv;
        pn[n][i] = v;
        pf[(size_t)row*DIMS_ + col] = v;
        s[i] += v; ss[i] += v*v;
      }
    }
#pragma unroll
    for (int i = 0; i < 4; ++i) {
      s[i] += __shfl_xor(s[i], 1, 16); ss[i] += __shfl_xor(ss[i], 1, 16);
      s[i] += __shfl_xor(s[i], 2, 16); ss[i] += __shfl_xor(ss[i], 2, 16);
      s[i] += __shfl_xor(s[i], 4, 16); ss[i] += __shfl_xor(ss[i], 4, 16);
      s[i] += __shfl_xor(s[i], 8, 16); ss[i] += __shfl_xor(ss[i], 8, 16);
    }
    float mu[4], rs[4];
#pragma unroll
    for (int i = 0; i < 4; ++i) {
      mu[i] = s[i]*(1.f/160.f);
      float var = ss[i]*(1.f/160.f) - mu[i]*mu[i];
      rs[i] = rsqrtf(var + 1e-5f);
    }
#pragma unroll
    for (int n = 0; n < 10; ++n) {
      int col = n*16 + r15;
      float gv = g1[col], bv = bt1[col];
#pragma unroll
      for (int i = 0; i < 4; ++i) {
        int row = 4*kg + i;
        float v = (pn[n][i] - mu[i])*rs[i]*gv + bv;
        int byte = row*384 + ((col*2) ^ ((row & 7) << 4));
        *(unsigned short*)(L1 + byte) = f2bf(v);
      }
    }
  }
  __syncthreads();

  // ---- phase 2: MLP1 (K=160, 20 col-tiles) + gelu -> L2
  fx4 acc2[20];
#pragma unroll
  for (int n = 0; n < 20; ++n) acc2[n] = (fx4){0.f,0.f,0.f,0.f};
#pragma unroll
  for (int t = 0; t < 5; ++t) {
    short8v a2 = *(const short8v*)(const void*)(L1 + r15*384 + ((t*64 + kg*16) ^ ((r15 & 7) << 4)));
#pragma unroll
    for (int n = 0; n < 20; ++n) {
      short8v bfr = *(const short8v*)(const void*)(w1 + (size_t)(n*16 + r15)*160 + t*32 + kg*8);
      acc2[n] = __builtin_amdgcn_mfma_f32_16x16x32_bf16(a2, bfr, acc2[n], 0, 0, 0);
    }
  }
#pragma unroll
  for (int n = 0; n < 20; ++n) {
    int col = n*16 + r15;
    float bv = b1v[col];
#pragma unroll
    for (int i = 0; i < 4; ++i) {
      float v = gelu_f(acc2[n][i] + bv);
      int row = 4*kg + i;
      int byte = row*640 + ((col*2) ^ ((row & 7) << 4));
      *(unsigned short*)(L2 + byte) = f2bf(v);
    }
  }
  __syncthreads();

  // ---- phase 3: MLP2 (K=320, 10 col-tiles) + residual (+ LN_next -> xn)
  float res[10][4];
#pragma unroll
  for (int n = 0; n < 10; ++n) {
    int col = n*16 + r15;
#pragma unroll
    for (int i = 0; i < 4; ++i)
      res[n][i] = pf[(size_t)(row0 + 4*kg + i)*DIMS_ + col];
  }
  fx4 acc3[10];
#pragma unroll
  for (int n = 0; n < 10; ++n) acc3[n] = (fx4){0.f,0.f,0.f,0.f};
#pragma unroll
  for (int t = 0; t < 10; ++t) {
    short8v a3 = *(const short8v*)(const void*)(L2 + r15*640 + ((t*64 + kg*16) ^ ((r15 & 7) << 4)));
#pragma unroll
    for (int n = 0; n < 10; ++n) {
      short8v bfr = *(const short8v*)(const void*)(w2 + (size_t)(n*16 + r15)*320 + t*32 + kg*8);
      acc3[n] = __builtin_amdgcn_mfma_f32_16x16x32_bf16(a3, bfr, acc3[n], 0, 0, 0);
    }
  }
  float s[4] = {0,0,0,0}, ss[4] = {0,0,0,0};
  float fnv[10][4];
#pragma unroll
  for (int n = 0; n < 10; ++n) {
    int col = n*16 + r15;
    float bv = b2v[col];
#pragma unroll
    for (int i = 0; i < 4; ++i) {
      float v = res[n][i] + acc3[n][i] + bv;
      fnv[n][i] = v;
      pf[(size_t)(row0 + 4*kg + i)*DIMS_ + col] = v;
      s[i] += v; ss[i] += v*v;
    }
  }
  if (HASNEXT) {
#pragma unroll
    for (int i = 0; i < 4; ++i) {
      s[i] += __shfl_xor(s[i], 1, 16); ss[i] += __shfl_xor(ss[i], 1, 16);
      s[i] += __shfl_xor(s[i], 2, 16); ss[i] += __shfl_xor(ss[i], 2, 16);
      s[i] += __shfl_xor(s[i], 4, 16); ss[i] += __shfl_xor(ss[i], 4, 16);
      s[i] += __shfl_xor(s[i], 8, 16); ss[i] += __shfl_xor(ss[i], 8, 16);
    }
#pragma unroll
    for (int n = 0; n < 10; ++n) {
      int col = n*16 + r15;
      float gv = gn[col], bv = btn[col];
#pragma unroll
      for (int i = 0; i < 4; ++i) {
        float mu = s[i]*(1.f/160.f);
        float var = ss[i]*(1.f/160.f) - mu*mu;
        float rsg = rsqrtf(var + 1e-5f);
        xn[(size_t)(row0 + 4*kg + i)*DIMS_ + col] = f2bf((fnv[n][i] - mu)*rsg*gv + bv);
      }
    }
  }
}

// ---------------- intra-patch attention: 1 wave = 16 queries, full MFMA ----------------
__global__ __launch_bounds__(64)
void intra_attn_mfma(const unsigned short* __restrict__ qb,
                     const unsigned short* __restrict__ kb,
                     const unsigned short* __restrict__ vt,
                     unsigned short* __restrict__ ab,
                     const int* __restrict__ cnt, const int* __restrict__ offs) {
  int r = blockIdx.y, b = blockIdx.z;
  int L = cnt[r];
  int q0 = blockIdx.x * 16;
  if (q0 >= L) return;
  int bo = b*PBB + offs[r];
  int lane = threadIdx.x, r15 = lane & 15, kg = lane >> 4;
  const float scale = 0.07905694150420949f;

  short8v qf[5];
  {
    const unsigned short* Qr = qb + (size_t)(bo + q0 + r15)*DIMS_ + kg*8;
#pragma unroll
    for (int kk = 0; kk < 5; ++kk)
      qf[kk] = *(const short8v*)(const void*)(Qr + kk*32);
  }

  int nkt = (L + 15) >> 4;
  int npv = (L + 31) >> 5;

  fx4 s[MAXT];
#pragma unroll
  for (int t = 0; t < MAXT; ++t) {
    if (t < nkt) {
      fx4 a = (fx4){0.f,0.f,0.f,0.f};
      const unsigned short* Kr = kb + (size_t)(bo + t*16 + r15)*DIMS_ + kg*8;
#pragma unroll
      for (int kk = 0; kk < 5; ++kk) {
        short8v kf = *(const short8v*)(const void*)(Kr + kk*32);
        a = __builtin_amdgcn_mfma_f32_16x16x32_bf16(qf[kk], kf, a, 0, 0, 0);
      }
      s[t] = a;
    }
  }

  float m0[4] = {-1e30f,-1e30f,-1e30f,-1e30f};
#pragma unroll
  for (int t = 0; t < MAXT; ++t) {
    if (t < nkt) {
      bool v = (t*16 + r15) < L;
#pragma unroll
      for (int i = 0; i < 4; ++i) {
        float sc = v ? s[t][i]*scale : -1e30f;
        s[t][i] = sc;
        m0[i] = fmaxf(m0[i], sc);
      }
    }
  }
#pragma unroll
  for (int i = 0; i < 4; ++i) {
    m0[i] = fmaxf(m0[i], __shfl_xor(m0[i], 1, 16));
    m0[i] = fmaxf(m0[i], __shfl_xor(m0[i], 2, 16));
    m0[i] = fmaxf(m0[i], __shfl_xor(m0[i], 4, 16));
    m0[i] = fmaxf(m0[i], __shfl_xor(m0[i], 8, 16));
  }
  float sum0[4] = {0.f,0.f,0.f,0.f};
#pragma unroll
  for (int t = 0; t < MAXT; ++t) {
    if (t < nkt) {
      bool v = (t*16 + r15) < L;
#pragma unroll
      for (int i = 0; i < 4; ++i) {
        float e = v ? expf(s[t][i] - m0[i]) : 0.f;
        s[t][i] = e; sum0[i] += e;
      }
    }
  }
#pragma unroll
  for (int i = 0; i < 4; ++i) {
    sum0[i] += __shfl_xor(sum0[i], 1, 16);
    sum0[i] += __shfl_xor(sum0[i], 2, 16);
    sum0[i] += __shfl_xor(sum0[i], 4, 16);
    sum0[i] += __shfl_xor(sum0[i], 8, 16);
  }

  __shared__ unsigned short Pl[16*256];
  char* Pb = (char*)Pl;
#pragma unroll
  for (int t = 0; t < MAXT; ++t) {
    if (t < nkt) {
#pragma unroll
      for (int i = 0; i < 4; ++i) {
        int row = 4*kg + i;
        int byte = row*512 + (((t*16 + r15)*2) ^ ((row & 7) << 4));
        *(unsigned short*)(Pb + byte) = f2bf(s[t][i]);
      }
    } else if (t*16 < npv*32) {
#pragma unroll
      for (int i = 0; i < 4; ++i) {
        int row = 4*kg + i;
        int byte = row*512 + (((t*16 + r15)*2) ^ ((row & 7) << 4));
        *(unsigned short*)(Pb + byte) = 0;
      }
    }
  }
  __syncthreads();

  fx4 o[10];
#pragma unroll
  for (int n = 0; n < 10; ++n) o[n] = (fx4){0.f,0.f,0.f,0.f};
#pragma unroll
  for (int sS = 0; sS < 8; ++sS) {
    if (sS < npv) {
      short8v pfr = *(const short8v*)(const void*)
          (Pb + r15*512 + ((sS*64 + kg*16) ^ ((r15 & 7) << 4)));
#pragma unroll
      for (int n = 0; n < 10; ++n) {
        const unsigned short* Vr = vt + (size_t)(n*16 + r15)*RMAXP + bo + sS*32 + kg*8;
        short8v vf = *(const short8v*)(const void*)Vr;
        o[n] = __builtin_amdgcn_mfma_f32_16x16x32_bf16(pfr, vf, o[n], 0, 0, 0);
      }
    }
  }

  float inv[4];
#pragma unroll
  for (int i = 0; i < 4; ++i) inv[i] = 1.f / sum0[i];
#pragma unroll
  for (int n = 0; n < 10; ++n) {
    int d = n*16 + r15;
#pragma unroll
    for (int i = 0; i < 4; ++i) {
      int q = q0 + 4*kg + i;
      if (q < L) ab[(size_t)(bo + q)*DIMS_ + d] = f2bf(o[n][i]*inv[i]);
    }
  }
}

// ---------------- inter-patch attention (<=8 keys), in-register, coalesced ----------------
__global__ __launch_bounds__(64)
void inter_attn(const unsigned short* __restrict__ qb,
                const unsigned short* __restrict__ kb,
                const unsigned short* __restrict__ vb,
                unsigned short* __restrict__ ab,
                const int* __restrict__ cnt, const int* __restrict__ offs,
                const int* __restrict__ cntmax) {
  int p = blockIdx.x, b = blockIdx.y;
  if (p >= cntmax[0]) return;
  int t = threadIdx.x;
  int i = t >> 3, j = t & 7;
  int cnti = cnt[i], cntj = cnt[j];
  int offi = offs[i], offj = offs[j];
  bool vi = p < cnti, vj = p < cntj;
  const float scale = 0.07905694150420949f;

  int rowi = b*PBB + (vi ? offi + p : 0);
  int rowj = b*PBB + (vj ? offj + p : 0);
  float sc;
  {
    const short8v* qr = (const short8v*)(qb + (size_t)rowi*DIMS_);
    const short8v* kr = (const short8v*)(kb + (size_t)rowj*DIMS_);
    float a = 0.f;
#pragma unroll
    for (int d8 = 0; d8 < 20; ++d8) {
      short8v a8 = qr[d8], b8 = kr[d8];
#pragma unroll
      for (int u = 0; u < 8; ++u)
        a += bf2f((unsigned short)a8[u]) * bf2f((unsigned short)b8[u]);
    }
    sc = (vi && vj) ? a * scale : -1e30f;
  }

  float m = sc;
  m = fmaxf(m, __shfl_xor(m, 1, 8));
  m = fmaxf(m, __shfl_xor(m, 2, 8));
  m = fmaxf(m, __shfl_xor(m, 4, 8));
  float e = (vi && vj) ? expf(sc - m) : 0.f;
  float ssum = e;
  ssum += __shfl_xor(ssum, 1, 8);
  ssum += __shfl_xor(ssum, 2, 8);
  ssum += __shfl_xor(ssum, 4, 8);
  float w = vi ? e / ssum : 0.f;

  bool act = t < 40;
  int d0 = t * 4;
  float vv[8][4];
#pragma unroll
  for (int j2 = 0; j2 < 8; ++j2) {
    int oj2 = __shfl(offj, j2);
    int cj2 = __shfl(cntj, j2);
    int rj2 = b*PBB + ((p < cj2) ? oj2 + p : 0);
    ushort4v v4 = {0,0,0,0};
    if (act) v4 = *(const ushort4v*)(const void*)(vb + (size_t)rj2*DIMS_ + d0);
    vv[j2][0] = bf2f(v4[0]); vv[j2][1] = bf2f(v4[1]);
    vv[j2][2] = bf2f(v4[2]); vv[j2][3] = bf2f(v4[3]);
  }
#pragma unroll
  for (int i2 = 0; i2 < 8; ++i2) {
    float a0=0.f, a1=0.f, a2=0.f, a3=0.f;
#pragma unroll
    for (int j2 = 0; j2 < 8; ++j2) {
      float wv = __shfl(w, i2*8 + j2);
      a0 += wv*vv[j2][0]; a1 += wv*vv[j2][1];
      a2 += wv*vv[j2][2]; a3 += wv*vv[j2][3];
    }
    int ci2 = __shfl(cnti, i2*8);
    int oi2 = __shfl(offi, i2*8);
    if (act && p < ci2) {
      ushort4v h;
      h[0]=f2bf(a0); h[1]=f2bf(a1); h[2]=f2bf(a2); h[3]=f2bf(a3);
      *(ushort4v*)(void*)(ab + (size_t)(b*PBB + oi2 + p)*DIMS_ + d0) = h;
    }
  }
}

// ---------------- final projection ----------------
__global__ __launch_bounds__(256)
void out_kernel(const float* __restrict__ pf, const float* __restrict__ outW,
                const float* __restrict__ outB, const int* __restrict__ pk,
                float* __restrict__ out) {
  int idx = blockIdx.x*256 + threadIdx.x;
  if (idx >= BB*12*NNODES) return;
  int n = idx % NNODES;
  int rest = idx / NNODES;
  int o = rest % 12;
  int b = rest / 12;
  int row = b*PBB + pk[n];
  const float4* Pr = (const float4*)&pf[(size_t)row*DIMS_];
  const float4* Wr = (const float4*)&outW[o*DIMS_];
  float ax=0.f, ay=0.f, az=0.f, aw=0.f;
#pragma unroll
  for (int d4 = 0; d4 < 40; ++d4) {
    float4 a = Pr[d4], c = Wr[d4];
    ax += a.x*c.x; ay += a.y*c.y; az += a.z*c.z; aw += a.w*c.w;
  }
  out[idx] = (ax+ay+az+aw) + outB[o];
}

extern "C" void kernel_launch(void* const* d_in, const int* in_sizes, int n_in,
                              void* d_out, int out_size, void* d_ws, size_t ws_size,
                              hipStream_t stream) {
  const float* x         = (const float*)d_in[0];
  const int*   te        = (const int*)d_in[1];
  const float* patch_emb = (const float*)d_in[2];
  const float* node_tab  = (const float*)d_in[3];
  const float* tod_emb   = (const float*)d_in[4];
  const float* dow_emb   = (const float*)d_in[5];
  const float* conv_W    = (const float*)d_in[6];
  const float* conv_b    = (const float*)d_in[7];
  const float* ln_scale  = (const float*)d_in[8];
  const float* ln_bias   = (const float*)d_in[9];
  const float* attn_W    = (const float*)d_in[10];
  const float* attn_b    = (const float*)d_in[11];
  const float* mlp_W1    = (const float*)d_in[12];
  const float* mlp_b1    = (const float*)d_in[13];
  const float* mlp_W2    = (const float*)d_in[14];
  const float* mlp_b2    = (const float*)d_in[15];
  const float* out_W     = (const float*)d_in[16];
  const float* out_b     = (const float*)d_in[17];

  float* out = (float*)d_out;
  float* probs_st = out + BB*12*NNODES;

  const size_t CY = (size_t)(RMAX2 + 16) * DIMS_;   // q/k slice stride (ushorts)

  char* W = (char*)d_ws;
  float* pf = (float*)W;                        W += (size_t)(RMAX2 + 16)*DIMS_*4;
  unsigned short* xn = (unsigned short*)W;      W += (size_t)(RMAX2 + 16)*DIMS_*2;
  unsigned short* qb = (unsigned short*)W;      W += CY*2;                       // q
  unsigned short* kb = (unsigned short*)W;      W += CY*2;                       // k (qb+CY)
  unsigned short* vt = (unsigned short*)W;      W += (size_t)DIMS_*RMAXP*2;      // v^T or v row-major (kb+CY)
  unsigned short* ab = (unsigned short*)W;      W += CY*2;
  unsigned short* wt_attn = (unsigned short*)W; W += (size_t)24*160*160*2;
  unsigned short* wt_w1   = (unsigned short*)W; W += (size_t)6*320*160*2;
  unsigned short* wt_w2   = (unsigned short*)W; W += (size_t)6*160*320*2;
  float* nsoft = (float*)W;                     W += (size_t)NNODES*32*4;
  int* patch_ids = (int*)W;
  int* pk     = patch_ids + NNODES;
  int* cnt    = pk + NNODES;
  int* offs   = cnt + 8;
  int* cntmax = offs + 8;

  // deterministic padding rows
  hipMemsetAsync(pf, 0, (size_t)(RMAX2 + 16)*DIMS_*4, stream);

  cvt_all<<<dim3(100, 36), 256, 0, stream>>>(attn_W, mlp_W1, mlp_W2, wt_attn, wt_w1, wt_w2);

  patch_kernel<<<(NNODES + 127)/128, 128, 0, stream>>>(node_tab, patch_emb, probs_st, nsoft, patch_ids);
  scan_kernel<<<1, 1024, 0, stream>>>(patch_ids, pk, cnt, offs, cntmax);
  embed_kernel<<<dim3(NNODES, BB), 160, 0, stream>>>(x, te, conv_W, conv_b, tod_emb, dow_emb, nsoft, pk, pf);

  const int GX = RMAX2 / 16;   // 472 row tiles

  // first xn = LN0(pf)
  ln_xn<<<GX, 64, 0, stream>>>(pf, ln_scale, ln_bias, xn);

  for (int l = 0; l < 3; ++l) {
    for (int a = 0; a < 2; ++a) {
      int wb = l*2 + a;
      const float* bbase = attn_b + (size_t)wb*4*DIMS_;
      const unsigned short* wqkv = wt_attn + (size_t)wb*4*25600;
      const float* g1  = ln_scale + (size_t)(l*4 + a*2 + 1)*DIMS_;
      const float* bt1 = ln_bias  + (size_t)(l*4 + a*2 + 1)*DIMS_;
      bool hasnext = !(l == 2 && a == 1);
      int nidx = (a == 0) ? (l*4 + 2) : ((l+1)*4);
      const float* gn  = hasnext ? ln_scale + (size_t)nidx*DIMS_ : nullptr;
      const float* btn = hasnext ? ln_bias  + (size_t)nidx*DIMS_ : nullptr;

      // QKV from xn (bf16): q,k row-major; V transposed (intra) or row-major (inter)
      if (a == 0)
        mfma_mm<160,true,5><<<dim3(GX,2,3), 64, 0, stream>>>(
            xn, wqkv, bbase, qb, RMAX2, DIMS_, 25600, CY, DIMS_);
      else
        mfma_mm<160,false,5><<<dim3(GX,2,3), 64, 0, stream>>>(
            xn, wqkv, bbase, qb, RMAX2, DIMS_, 25600, CY, DIMS_);

      if (a == 0)
        intra_attn_mfma<<<dim3(16, 8, BB), 64, 0, stream>>>(qb, kb, vt, ab, cnt, offs);
      else
        inter_attn<<<dim3(NNODES, BB), 64, 0, stream>>>(qb, kb, vt, ab, cnt, offs, cntmax);

      // fused proj + residual + LN + MLP1 + MLP2 + residual + LN_next
      const unsigned short* wproj = wqkv + 3*25600;
      const float* bproj = bbase + 3*DIMS_;
      const unsigned short* w1 = wt_w1 + (size_t)wb*51200;
      const unsigned short* w2 = wt_w2 + (size_t)wb*51200;
      const float* b1v = mlp_b1 + (size_t)wb*HID_;
      const float* b2v = mlp_b2 + (size_t)wb*DIMS_;
      if (hasnext)
        fused_mlp<true><<<GX, 64, 0, stream>>>(ab, wproj, bproj, w1, b1v, w2, b2v,
                                               g1, bt1, gn, btn, pf, xn);
      else
        fused_mlp<false><<<GX, 64, 0, stream>>>(ab, wproj, bproj, w1, b1v, w2, b2v,
                                                g1, bt1, nullptr, nullptr, pf, xn);
    }
  }

  out_kernel<<<(BB*12*NNODES + 255)/256, 256, 0, stream>>>(pf, out_W, out_b, pk, out);
}

// Round 10
// 382.213 us; speedup vs baseline: 1.2651x; 1.2651x over previous
//
#include <hip/hip_runtime.h>
#include <math.h>

#define NNODES 883
#define BB 8
#define DIMS_ 160
#define HID_ 320
#define PBB 944                 // padded rows per batch (patch offsets aligned to 8)
#define RMAX2 (BB*PBB)          // 7552 packed rows incl. padding
#define RMAXP (RMAX2+64)        // vt row stride
#define MAXT 16

typedef __attribute__((ext_vector_type(8))) short short8v;   // 8 bf16 in 4 VGPRs
typedef __attribute__((ext_vector_type(4))) float fx4;
typedef __attribute__((ext_vector_type(4))) unsigned short ushort4v;

__device__ __forceinline__ unsigned short f2bf(float f) {
  unsigned int u = __float_as_uint(f);
  u = (u + 0x7fffu + ((u >> 16) & 1u)) >> 16;   // RNE
  return (unsigned short)u;
}
__device__ __forceinline__ float bf2f(unsigned short u) {
  return __uint_as_float(((unsigned int)u) << 16);
}
__device__ __forceinline__ float gelu_f(float v) {
  return 0.5f*v*(1.f + erff(v*0.70710678118654752f));
}

// ---------------- patch assignment ----------------
__global__ __launch_bounds__(128)
void patch_kernel(const float* __restrict__ node_table,
                  const float* __restrict__ patch_emb,
                  float* __restrict__ probs_st,
                  float* __restrict__ nsoft,
                  int* __restrict__ patch_ids) {
  int n = blockIdx.x * blockDim.x + threadIdx.x;
  if (n >= NNODES) return;
  float nt[32];
#pragma unroll
  for (int j = 0; j < 32; ++j) nt[j] = node_table[n*32 + j];
  float lg[8];
#pragma unroll
  for (int r = 0; r < 8; ++r) {
    float a = 0.f;
#pragma unroll
    for (int j = 0; j < 32; ++j) a += nt[j] * patch_emb[r*32 + j];
    lg[r] = a;
  }
  float m = lg[0];
#pragma unroll
  for (int r = 1; r < 8; ++r) m = fmaxf(m, lg[r]);
  float e[8]; float s = 0.f;
#pragma unroll
  for (int r = 0; r < 8; ++r) { e[r] = expf(lg[r] - m); s += e[r]; }
  float p[8];
#pragma unroll
  for (int r = 0; r < 8; ++r) p[r] = e[r] / s;
  int am = 0; float best = p[0];
#pragma unroll
  for (int r = 1; r < 8; ++r) if (p[r] > best) { best = p[r]; am = r; }
  patch_ids[n] = am;
#pragma unroll
  for (int r = 0; r < 8; ++r) {
    float hard = (r == am) ? 1.f : 0.f;
    probs_st[n*8 + r] = (hard - p[r]) + p[r];
  }
#pragma unroll
  for (int j = 0; j < 32; ++j) {
    float a = 0.f;
#pragma unroll
    for (int r = 0; r < 8; ++r) a += p[r] * patch_emb[r*32 + j];
    nsoft[n*32 + j] = a;
  }
}

// ---------------- parallel scan (patch offsets aligned to 8 rows) ----------------
__global__ __launch_bounds__(1024)
void scan_kernel(const int* __restrict__ patch_ids,
                 int* __restrict__ pk, int* __restrict__ cnt,
                 int* __restrict__ offs, int* __restrict__ cntmax) {
  __shared__ int pid_s[NNODES];
  __shared__ int cnt_s[8], offs_s[8];
  int t = threadIdx.x;
  if (t < 8) cnt_s[t] = 0;
  for (int n = t; n < NNODES; n += 1024) pid_s[n] = patch_ids[n];
  __syncthreads();
  int p = -1, pos = 0;
  if (t < NNODES) {
    p = pid_s[t];
    atomicAdd(&cnt_s[p], 1);
    for (int m = 0; m < t; ++m) pos += (pid_s[m] == p) ? 1 : 0;
  }
  __syncthreads();
  if (t == 0) {
    int o = 0, mx = 0;
#pragma unroll
    for (int r = 0; r < 8; ++r) {
      offs_s[r] = o; offs[r] = o; cnt[r] = cnt_s[r];
      if (cnt_s[r] > mx) mx = cnt_s[r];
      o += (cnt_s[r] + 7) & ~7;
    }
    cntmax[0] = mx;
  }
  __syncthreads();
  if (t < NNODES) pk[t] = offs_s[p] + pos;
}

// ---------------- embedding ----------------
__global__ __launch_bounds__(160)
void embed_kernel(const float* __restrict__ x, const int* __restrict__ te,
                  const float* __restrict__ convW, const float* __restrict__ convB,
                  const float* __restrict__ tod, const float* __restrict__ dow,
                  const float* __restrict__ nsoft, const int* __restrict__ pk,
                  float* __restrict__ pf) {
  int n = blockIdx.x, b = blockIdx.y, t = threadIdx.x;
  __shared__ float xs[3][12];
  if (t < 12) {
    int l = t;
    xs[0][l] = x[(b*12 + l)*NNODES + n];
    int base = ((b*12 + l)*NNODES + n)*2;
    xs[1][l] = (float)te[base]     / 288.0f;
    xs[2][l] = (float)te[base + 1] / 7.0f;
  }
  __syncthreads();
  int row = b*PBB + pk[n];
  float val;
  if (t < 64) {
    float a = convB[t];
#pragma unroll
    for (int c = 0; c < 3; ++c)
#pragma unroll
      for (int l = 0; l < 12; ++l)
        a += xs[c][l] * convW[t*36 + c*12 + l];
    val = a;
  } else if (t < 96) {
    int ti = te[((b*12 + 11)*NNODES + n)*2 + 0];
    val = tod[ti*32 + (t - 64)];
  } else if (t < 128) {
    int dw = te[((b*12 + 11)*NNODES + n)*2 + 1];
    val = dow[dw*32 + (t - 96)];
  } else {
    val = nsoft[n*32 + (t - 128)];
  }
  pf[row*DIMS_ + t] = val;
}

// ---------------- all weight converts in one launch (transpose to bf16 [N][K]) ----------------
__global__ __launch_bounds__(256)
void cvt_all(const float* __restrict__ attn_W, const float* __restrict__ mlp_W1,
             const float* __restrict__ mlp_W2,
             unsigned short* __restrict__ wt_attn, unsigned short* __restrict__ wt_w1,
             unsigned short* __restrict__ wt_w2) {
  int y = blockIdx.y;
  const float* src; unsigned short* dst; int K, N;
  if (y < 24)      { src = attn_W + (size_t)y*25600;        dst = wt_attn + (size_t)y*25600; K = 160; N = 160; }
  else if (y < 30) { int q = y-24; src = mlp_W1 + (size_t)q*160*320; dst = wt_w1 + (size_t)q*51200; K = 160; N = 320; }
  else             { int q = y-30; src = mlp_W2 + (size_t)q*320*160; dst = wt_w2 + (size_t)q*51200; K = 320; N = 160; }
  int total = K*N;
  for (int idx = blockIdx.x*256 + threadIdx.x; idx < total; idx += gridDim.x*256) {
    int n = idx / K, k = idx - n*K;
    dst[idx] = f2bf(src[(size_t)k*N + n]);
  }
}

// ---------------- standalone LN -> bf16 xn (first block only) ----------------
__global__ __launch_bounds__(64)
void ln_xn(const float* __restrict__ pf, const float* __restrict__ g,
           const float* __restrict__ bt, unsigned short* __restrict__ xn) {
  int lane = threadIdx.x, r15 = lane & 15, kg = lane >> 4;
  int row0 = blockIdx.x * 16;
  float v[10][4];
  float s[4] = {0,0,0,0}, ss[4] = {0,0,0,0};
#pragma unroll
  for (int n = 0; n < 10; ++n) {
    int col = n*16 + r15;
#pragma unroll
    for (int i = 0; i < 4; ++i) {
      float xv = pf[(size_t)(row0 + 4*kg + i)*DIMS_ + col];
      v[n][i] = xv; s[i] += xv; ss[i] += xv*xv;
    }
  }
#pragma unroll
  for (int i = 0; i < 4; ++i) {
    s[i] += __shfl_xor(s[i], 1, 16); ss[i] += __shfl_xor(ss[i], 1, 16);
    s[i] += __shfl_xor(s[i], 2, 16); ss[i] += __shfl_xor(ss[i], 2, 16);
    s[i] += __shfl_xor(s[i], 4, 16); ss[i] += __shfl_xor(ss[i], 4, 16);
    s[i] += __shfl_xor(s[i], 8, 16); ss[i] += __shfl_xor(ss[i], 8, 16);
  }
#pragma unroll
  for (int n = 0; n < 10; ++n) {
    int col = n*16 + r15;
    float gv = g[col], bv = bt[col];
#pragma unroll
    for (int i = 0; i < 4; ++i) {
      float mu = s[i]*(1.f/160.f);
      float var = ss[i]*(1.f/160.f) - mu*mu;
      float rs = rsqrtf(var + 1e-5f);
      xn[(size_t)(row0 + 4*kg + i)*DIMS_ + col] = f2bf((v[n][i] - mu)*rs*gv + bv);
    }
  }
}

// ---------------- MFMA matmul (QKV): bf16 in, bf16 out, one wave = 16 rows x 80 cols ----------------
template<int K, bool TRANSV, int CT>
__global__ __launch_bounds__(64)
void mfma_mm(const unsigned short* __restrict__ Xv, const unsigned short* __restrict__ Wt,
             const float* __restrict__ bias, unsigned short* __restrict__ Cv,
             int M, int Cstride, size_t Wystep, size_t Cystep, int bystep) {
  constexpr int NS = K / 32;
  int lane = threadIdx.x;
  int r15  = lane & 15;
  int kg   = lane >> 4;
  int row0 = blockIdx.x * 16;
  int colbase = blockIdx.y * (CT*16);
  int z = blockIdx.z;
  Wt   += (size_t)z * Wystep;
  bias += (size_t)z * bystep;

  int ar = row0 + r15; if (ar > M-1) ar = M-1;
  short8v afrag[NS];
  const unsigned short* Xr = Xv + (size_t)ar*K + kg*8;
#pragma unroll
  for (int t = 0; t < NS; ++t)
    afrag[t] = *(const short8v*)(const void*)(Xr + t*32);

  fx4 acc[CT];
#pragma unroll
  for (int n = 0; n < CT; ++n) acc[n] = (fx4){0.f,0.f,0.f,0.f};

  const unsigned short* Wb = Wt + (size_t)(colbase + r15)*K + kg*8;
#pragma unroll
  for (int t = 0; t < NS; ++t)
#pragma unroll
    for (int n = 0; n < CT; ++n) {
      short8v bfr = *(const short8v*)(const void*)(Wb + (size_t)n*16*K + t*32);
      acc[n] = __builtin_amdgcn_mfma_f32_16x16x32_bf16(afrag[t], bfr, acc[n], 0, 0, 0);
    }

  int orow0 = row0 + kg*4;
  unsigned short* C = Cv + (size_t)z * Cystep;
#pragma unroll
  for (int n = 0; n < CT; ++n) {
    int col = colbase + n*16 + r15;
    float bv = bias[col];
#pragma unroll
    for (int i = 0; i < 4; ++i) {
      int rr = orow0 + i;
      if (rr >= M) continue;
      unsigned short h = f2bf(acc[n][i] + bv);
      if (TRANSV && z == 2) C[(size_t)col*RMAXP + rr] = h;
      else                  C[(size_t)rr*Cstride + col] = h;
    }
  }
}

// ---------------- fused proj+residual+LN+MLP1(gelu)+MLP2+residual+LN_next ----------------
// 256 threads = 4 waves over the SAME 16 rows; N-tiles column-split across waves.
// proj & MLP2 tiles: n = wid + 4u (u<3, n<10)  [identical assignment so trunk stays in regs]
// MLP1 tiles:        n = wid + 4u (u<5, n<20)
template<bool HASNEXT>
__global__ __launch_bounds__(256)
void fused_mlp(const unsigned short* __restrict__ ab,
               const unsigned short* __restrict__ wproj, const float* __restrict__ bproj,
               const unsigned short* __restrict__ w1, const float* __restrict__ b1v,
               const unsigned short* __restrict__ w2, const float* __restrict__ b2v,
               const float* __restrict__ g1, const float* __restrict__ bt1,
               const float* __restrict__ gn, const float* __restrict__ btn,
               float* __restrict__ pf, unsigned short* __restrict__ xn) {
  __shared__ unsigned short L1s[16*192];   // 16 rows x 384 B
  __shared__ unsigned short L2s[16*320];   // 16 rows x 640 B
  __shared__ float sA[4][16], ssA[4][16];
  char* L1 = (char*)L1s; char* L2 = (char*)L2s;
  int tid = threadIdx.x;
  int wid = tid >> 6;
  int lane = tid & 63;
  int r15 = lane & 15, kg = lane >> 4;
  int row0 = blockIdx.x * 16;
  int nt1 = (wid < 2) ? 3 : 2;             // proj/MLP2 tiles this wave owns

  // ---- phase 1: proj
  short8v af[5];
  {
    const unsigned short* Ar = ab + (size_t)(row0 + r15)*DIMS_ + kg*8;
#pragma unroll
    for (int t = 0; t < 5; ++t) af[t] = *(const short8v*)(const void*)(Ar + t*32);
  }
  fx4 acc[3];
#pragma unroll
  for (int u = 0; u < 3; ++u) acc[u] = (fx4){0.f,0.f,0.f,0.f};
#pragma unroll
  for (int t = 0; t < 5; ++t)
#pragma unroll
    for (int u = 0; u < 3; ++u)
      if (u < nt1) {
        int n = wid + 4*u;
        short8v bfr = *(const short8v*)(const void*)(wproj + (size_t)(n*16 + r15)*160 + t*32 + kg*8);
        acc[u] = __builtin_amdgcn_mfma_f32_16x16x32_bf16(af[t], bfr, acc[u], 0, 0, 0);
      }

  // residual + store pf + stats
  float pn[3][4];
  float sv[4] = {0,0,0,0}, ssv[4] = {0,0,0,0};
#pragma unroll
  for (int u = 0; u < 3; ++u)
    if (u < nt1) {
      int n = wid + 4*u;
      int col = n*16 + r15;
      float bv = bproj[col];
#pragma unroll
      for (int i = 0; i < 4; ++i) {
        int row = row0 + 4*kg + i;
        float v = pf[(size_t)row*DIMS_ + col] + acc[u][i] + bv;
        pn[u][i] = v;
        pf[(size_t)row*DIMS_ + col] = v;
        sv[i] += v; ssv[i] += v*v;
      }
    }
#pragma unroll
  for (int i = 0; i < 4; ++i) {
    sv[i] += __shfl_xor(sv[i], 1, 16); ssv[i] += __shfl_xor(ssv[i], 1, 16);
    sv[i] += __shfl_xor(sv[i], 2, 16); ssv[i] += __shfl_xor(ssv[i], 2, 16);
    sv[i] += __shfl_xor(sv[i], 4, 16); ssv[i] += __shfl_xor(ssv[i], 4, 16);
    sv[i] += __shfl_xor(sv[i], 8, 16); ssv[i] += __shfl_xor(ssv[i], 8, 16);
  }
  if (r15 == 0) {
#pragma unroll
    for (int i = 0; i < 4; ++i) { sA[wid][4*kg+i] = sv[i]; ssA[wid][4*kg+i] = ssv[i]; }
  }
  __syncthreads();
  float mu[4], rs[4];
#pragma unroll
  for (int i = 0; i < 4; ++i) {
    float st  = sA[0][4*kg+i]  + sA[1][4*kg+i]  + sA[2][4*kg+i]  + sA[3][4*kg+i];
    float sst = ssA[0][4*kg+i] + ssA[1][4*kg+i] + ssA[2][4*kg+i] + ssA[3][4*kg+i];
    mu[i] = st*(1.f/160.f);
    float var = sst*(1.f/160.f) - mu[i]*mu[i];
    rs[i] = rsqrtf(var + 1e-5f);
  }
#pragma unroll
  for (int u = 0; u < 3; ++u)
    if (u < nt1) {
      int n = wid + 4*u;
      int col = n*16 + r15;
      float gv = g1[col], bv = bt1[col];
#pragma unroll
      for (int i = 0; i < 4; ++i) {
        int row = 4*kg + i;
        int byte = row*384 + ((col*2) ^ ((row & 7) << 4));
        *(unsigned short*)(L1 + byte) = f2bf((pn[u][i] - mu[i])*rs[i]*gv + bv);
      }
    }
  __syncthreads();

  // ---- phase 2: MLP1 (20 tiles, 5 per wave) + gelu -> L2
  fx4 acc2[5];
#pragma unroll
  for (int u = 0; u < 5; ++u) acc2[u] = (fx4){0.f,0.f,0.f,0.f};
#pragma unroll
  for (int t = 0; t < 5; ++t) {
    short8v a2 = *(const short8v*)(const void*)(L1 + r15*384 + ((t*64 + kg*16) ^ ((r15 & 7) << 4)));
#pragma unroll
    for (int u = 0; u < 5; ++u) {
      int n = wid + 4*u;
      short8v bfr = *(const short8v*)(const void*)(w1 + (size_t)(n*16 + r15)*160 + t*32 + kg*8);
      acc2[u] = __builtin_amdgcn_mfma_f32_16x16x32_bf16(a2, bfr, acc2[u], 0, 0, 0);
    }
  }
#pragma unroll
  for (int u = 0; u < 5; ++u) {
    int n = wid + 4*u;
    int col = n*16 + r15;
    float bv = b1v[col];
#pragma unroll
    for (int i = 0; i < 4; ++i) {
      float v = gelu_f(acc2[u][i] + bv);
      int row = 4*kg + i;
      int byte = row*640 + ((col*2) ^ ((row & 7) << 4));
      *(unsigned short*)(L2 + byte) = f2bf(v);
    }
  }
  __syncthreads();

  // ---- phase 3: MLP2 (10 tiles, same assignment as proj) + residual (+ LN_next)
  fx4 acc3[3];
#pragma unroll
  for (int u = 0; u < 3; ++u) acc3[u] = (fx4){0.f,0.f,0.f,0.f};
#pragma unroll
  for (int t = 0; t < 10; ++t) {
    short8v a3 = *(const short8v*)(const void*)(L2 + r15*640 + ((t*64 + kg*16) ^ ((r15 & 7) << 4)));
#pragma unroll
    for (int u = 0; u < 3; ++u)
      if (u < nt1) {
        int n = wid + 4*u;
        short8v bfr = *(const short8v*)(const void*)(w2 + (size_t)(n*16 + r15)*320 + t*32 + kg*8);
        acc3[u] = __builtin_amdgcn_mfma_f32_16x16x32_bf16(a3, bfr, acc3[u], 0, 0, 0);
      }
  }
  float sv2[4] = {0,0,0,0}, ssv2[4] = {0,0,0,0};
  float fnv[3][4];
#pragma unroll
  for (int u = 0; u < 3; ++u)
    if (u < nt1) {
      int n = wid + 4*u;
      int col = n*16 + r15;
      float bv = b2v[col];
#pragma unroll
      for (int i = 0; i < 4; ++i) {
        float v = pn[u][i] + acc3[u][i] + bv;   // trunk residual from registers
        fnv[u][i] = v;
        pf[(size_t)(row0 + 4*kg + i)*DIMS_ + col] = v;
        sv2[i] += v; ssv2[i] += v*v;
      }
    }
  if (HASNEXT) {
#pragma unroll
    for (int i = 0; i < 4; ++i) {
      sv2[i] += __shfl_xor(sv2[i], 1, 16); ssv2[i] += __shfl_xor(ssv2[i], 1, 16);
      sv2[i] += __shfl_xor(sv2[i], 2, 16); ssv2[i] += __shfl_xor(ssv2[i], 2, 16);
      sv2[i] += __shfl_xor(sv2[i], 4, 16); ssv2[i] += __shfl_xor(ssv2[i], 4, 16);
      sv2[i] += __shfl_xor(sv2[i], 8, 16); ssv2[i] += __shfl_xor(ssv2[i], 8, 16);
    }
    if (r15 == 0) {
#pragma unroll
      for (int i = 0; i < 4; ++i) { sA[wid][4*kg+i] = sv2[i]; ssA[wid][4*kg+i] = ssv2[i]; }
    }
    __syncthreads();
#pragma unroll
    for (int i = 0; i < 4; ++i) {
      float st  = sA[0][4*kg+i]  + sA[1][4*kg+i]  + sA[2][4*kg+i]  + sA[3][4*kg+i];
      float sst = ssA[0][4*kg+i] + ssA[1][4*kg+i] + ssA[2][4*kg+i] + ssA[3][4*kg+i];
      mu[i] = st*(1.f/160.f);
      float var = sst*(1.f/160.f) - mu[i]*mu[i];
      rs[i] = rsqrtf(var + 1e-5f);
    }
#pragma unroll
    for (int u = 0; u < 3; ++u)
      if (u < nt1) {
        int n = wid + 4*u;
        int col = n*16 + r15;
        float gv = gn[col], bv = btn[col];
#pragma unroll
        for (int i = 0; i < 4; ++i)
          xn[(size_t)(row0 + 4*kg + i)*DIMS_ + col] = f2bf((fnv[u][i] - mu[i])*rs[i]*gv + bv);
      }
  }
}

// ---------------- intra-patch attention: 1 wave = 16 queries, full MFMA ----------------
__global__ __launch_bounds__(64)
void intra_attn_mfma(const unsigned short* __restrict__ qb,
                     const unsigned short* __restrict__ kb,
                     const unsigned short* __restrict__ vt,
                     unsigned short* __restrict__ ab,
                     const int* __restrict__ cnt, const int* __restrict__ offs) {
  int r = blockIdx.y, b = blockIdx.z;
  int L = cnt[r];
  int q0 = blockIdx.x * 16;
  if (q0 >= L) return;
  int bo = b*PBB + offs[r];
  int lane = threadIdx.x, r15 = lane & 15, kg = lane >> 4;
  const float scale = 0.07905694150420949f;

  short8v qf[5];
  {
    const unsigned short* Qr = qb + (size_t)(bo + q0 + r15)*DIMS_ + kg*8;
#pragma unroll
    for (int kk = 0; kk < 5; ++kk)
      qf[kk] = *(const short8v*)(const void*)(Qr + kk*32);
  }

  int nkt = (L + 15) >> 4;
  int npv = (L + 31) >> 5;

  fx4 s[MAXT];
#pragma unroll
  for (int t = 0; t < MAXT; ++t) {
    if (t < nkt) {
      fx4 a = (fx4){0.f,0.f,0.f,0.f};
      const unsigned short* Kr = kb + (size_t)(bo + t*16 + r15)*DIMS_ + kg*8;
#pragma unroll
      for (int kk = 0; kk < 5; ++kk) {
        short8v kf = *(const short8v*)(const void*)(Kr + kk*32);
        a = __builtin_amdgcn_mfma_f32_16x16x32_bf16(qf[kk], kf, a, 0, 0, 0);
      }
      s[t] = a;
    }
  }

  float m0[4] = {-1e30f,-1e30f,-1e30f,-1e30f};
#pragma unroll
  for (int t = 0; t < MAXT; ++t) {
    if (t < nkt) {
      bool v = (t*16 + r15) < L;
#pragma unroll
      for (int i = 0; i < 4; ++i) {
        float sc = v ? s[t][i]*scale : -1e30f;
        s[t][i] = sc;
        m0[i] = fmaxf(m0[i], sc);
      }
    }
  }
#pragma unroll
  for (int i = 0; i < 4; ++i) {
    m0[i] = fmaxf(m0[i], __shfl_xor(m0[i], 1, 16));
    m0[i] = fmaxf(m0[i], __shfl_xor(m0[i], 2, 16));
    m0[i] = fmaxf(m0[i], __shfl_xor(m0[i], 4, 16));
    m0[i] = fmaxf(m0[i], __shfl_xor(m0[i], 8, 16));
  }
  float sum0[4] = {0.f,0.f,0.f,0.f};
#pragma unroll
  for (int t = 0; t < MAXT; ++t) {
    if (t < nkt) {
      bool v = (t*16 + r15) < L;
#pragma unroll
      for (int i = 0; i < 4; ++i) {
        float e = v ? expf(s[t][i] - m0[i]) : 0.f;
        s[t][i] = e; sum0[i] += e;
      }
    }
  }
#pragma unroll
  for (int i = 0; i < 4; ++i) {
    sum0[i] += __shfl_xor(sum0[i], 1, 16);
    sum0[i] += __shfl_xor(sum0[i], 2, 16);
    sum0[i] += __shfl_xor(sum0[i], 4, 16);
    sum0[i] += __shfl_xor(sum0[i], 8, 16);
  }

  __shared__ unsigned short Pl[16*256];
  char* Pb = (char*)Pl;
#pragma unroll
  for (int t = 0; t < MAXT; ++t) {
    if (t < nkt) {
#pragma unroll
      for (int i = 0; i < 4; ++i) {
        int row = 4*kg + i;
        int byte = row*512 + (((t*16 + r15)*2) ^ ((row & 7) << 4));
        *(unsigned short*)(Pb + byte) = f2bf(s[t][i]);
      }
    } else if (t*16 < npv*32) {
#pragma unroll
      for (int i = 0; i < 4; ++i) {
        int row = 4*kg + i;
        int byte = row*512 + (((t*16 + r15)*2) ^ ((row & 7) << 4));
        *(unsigned short*)(Pb + byte) = 0;
      }
    }
  }
  __syncthreads();

  fx4 o[10];
#pragma unroll
  for (int n = 0; n < 10; ++n) o[n] = (fx4){0.f,0.f,0.f,0.f};
#pragma unroll
  for (int sS = 0; sS < 8; ++sS) {
    if (sS < npv) {
      short8v pfr = *(const short8v*)(const void*)
          (Pb + r15*512 + ((sS*64 + kg*16) ^ ((r15 & 7) << 4)));
#pragma unroll
      for (int n = 0; n < 10; ++n) {
        const unsigned short* Vr = vt + (size_t)(n*16 + r15)*RMAXP + bo + sS*32 + kg*8;
        short8v vf = *(const short8v*)(const void*)Vr;
        o[n] = __builtin_amdgcn_mfma_f32_16x16x32_bf16(pfr, vf, o[n], 0, 0, 0);
      }
    }
  }

  float inv[4];
#pragma unroll
  for (int i = 0; i < 4; ++i) inv[i] = 1.f / sum0[i];
#pragma unroll
  for (int n = 0; n < 10; ++n) {
    int d = n*16 + r15;
#pragma unroll
    for (int i = 0; i < 4; ++i) {
      int q = q0 + 4*kg + i;
      if (q < L) ab[(size_t)(bo + q)*DIMS_ + d] = f2bf(o[n][i]*inv[i]);
    }
  }
}

// ---------------- inter-patch attention (<=8 keys), in-register, coalesced ----------------
__global__ __launch_bounds__(64)
void inter_attn(const unsigned short* __restrict__ qb,
                const unsigned short* __restrict__ kb,
                const unsigned short* __restrict__ vb,
                unsigned short* __restrict__ ab,
                const int* __restrict__ cnt, const int* __restrict__ offs,
                const int* __restrict__ cntmax) {
  int p = blockIdx.x, b = blockIdx.y;
  if (p >= cntmax[0]) return;
  int t = threadIdx.x;
  int i = t >> 3, j = t & 7;
  int cnti = cnt[i], cntj = cnt[j];
  int offi = offs[i], offj = offs[j];
  bool vi = p < cnti, vj = p < cntj;
  const float scale = 0.07905694150420949f;

  int rowi = b*PBB + (vi ? offi + p : 0);
  int rowj = b*PBB + (vj ? offj + p : 0);
  float sc;
  {
    const short8v* qr = (const short8v*)(qb + (size_t)rowi*DIMS_);
    const short8v* kr = (const short8v*)(kb + (size_t)rowj*DIMS_);
    float a = 0.f;
#pragma unroll
    for (int d8 = 0; d8 < 20; ++d8) {
      short8v a8 = qr[d8], b8 = kr[d8];
#pragma unroll
      for (int u = 0; u < 8; ++u)
        a += bf2f((unsigned short)a8[u]) * bf2f((unsigned short)b8[u]);
    }
    sc = (vi && vj) ? a * scale : -1e30f;
  }

  float m = sc;
  m = fmaxf(m, __shfl_xor(m, 1, 8));
  m = fmaxf(m, __shfl_xor(m, 2, 8));
  m = fmaxf(m, __shfl_xor(m, 4, 8));
  float e = (vi && vj) ? expf(sc - m) : 0.f;
  float ssum = e;
  ssum += __shfl_xor(ssum, 1, 8);
  ssum += __shfl_xor(ssum, 2, 8);
  ssum += __shfl_xor(ssum, 4, 8);
  float w = vi ? e / ssum : 0.f;

  bool act = t < 40;
  int d0 = t * 4;
  float vv[8][4];
#pragma unroll
  for (int j2 = 0; j2 < 8; ++j2) {
    int oj2 = __shfl(offj, j2);
    int cj2 = __shfl(cntj, j2);
    int rj2 = b*PBB + ((p < cj2) ? oj2 + p : 0);
    ushort4v v4 = {0,0,0,0};
    if (act) v4 = *(const ushort4v*)(const void*)(vb + (size_t)rj2*DIMS_ + d0);
    vv[j2][0] = bf2f(v4[0]); vv[j2][1] = bf2f(v4[1]);
    vv[j2][2] = bf2f(v4[2]); vv[j2][3] = bf2f(v4[3]);
  }
#pragma unroll
  for (int i2 = 0; i2 < 8; ++i2) {
    float a0=0.f, a1=0.f, a2=0.f, a3=0.f;
#pragma unroll
    for (int j2 = 0; j2 < 8; ++j2) {
      float wv = __shfl(w, i2*8 + j2);
      a0 += wv*vv[j2][0]; a1 += wv*vv[j2][1];
      a2 += wv*vv[j2][2]; a3 += wv*vv[j2][3];
    }
    int ci2 = __shfl(cnti, i2*8);
    int oi2 = __shfl(offi, i2*8);
    if (act && p < ci2) {
      ushort4v h;
      h[0]=f2bf(a0); h[1]=f2bf(a1); h[2]=f2bf(a2); h[3]=f2bf(a3);
      *(ushort4v*)(void*)(ab + (size_t)(b*PBB + oi2 + p)*DIMS_ + d0) = h;
    }
  }
}

// ---------------- final projection ----------------
__global__ __launch_bounds__(256)
void out_kernel(const float* __restrict__ pf, const float* __restrict__ outW,
                const float* __restrict__ outB, const int* __restrict__ pk,
                float* __restrict__ out) {
  int idx = blockIdx.x*256 + threadIdx.x;
  if (idx >= BB*12*NNODES) return;
  int n = idx % NNODES;
  int rest = idx / NNODES;
  int o = rest % 12;
  int b = rest / 12;
  int row = b*PBB + pk[n];
  const float4* Pr = (const float4*)&pf[(size_t)row*DIMS_];
  const float4* Wr = (const float4*)&outW[o*DIMS_];
  float ax=0.f, ay=0.f, az=0.f, aw=0.f;
#pragma unroll
  for (int d4 = 0; d4 < 40; ++d4) {
    float4 a = Pr[d4], c = Wr[d4];
    ax += a.x*c.x; ay += a.y*c.y; az += a.z*c.z; aw += a.w*c.w;
  }
  out[idx] = (ax+ay+az+aw) + outB[o];
}

extern "C" void kernel_launch(void* const* d_in, const int* in_sizes, int n_in,
                              void* d_out, int out_size, void* d_ws, size_t ws_size,
                              hipStream_t stream) {
  const float* x         = (const float*)d_in[0];
  const int*   te        = (const int*)d_in[1];
  const float* patch_emb = (const float*)d_in[2];
  const float* node_tab  = (const float*)d_in[3];
  const float* tod_emb   = (const float*)d_in[4];
  const float* dow_emb   = (const float*)d_in[5];
  const float* conv_W    = (const float*)d_in[6];
  const float* conv_b    = (const float*)d_in[7];
  const float* ln_scale  = (const float*)d_in[8];
  const float* ln_bias   = (const float*)d_in[9];
  const float* attn_W    = (const float*)d_in[10];
  const float* attn_b    = (const float*)d_in[11];
  const float* mlp_W1    = (const float*)d_in[12];
  const float* mlp_b1    = (const float*)d_in[13];
  const float* mlp_W2    = (const float*)d_in[14];
  const float* mlp_b2    = (const float*)d_in[15];
  const float* out_W     = (const float*)d_in[16];
  const float* out_b     = (const float*)d_in[17];

  float* out = (float*)d_out;
  float* probs_st = out + BB*12*NNODES;

  const size_t CY = (size_t)(RMAX2 + 16) * DIMS_;   // q/k slice stride (ushorts)

  char* W = (char*)d_ws;
  float* pf = (float*)W;                        W += (size_t)(RMAX2 + 16)*DIMS_*4;
  unsigned short* xn = (unsigned short*)W;      W += (size_t)(RMAX2 + 16)*DIMS_*2;
  unsigned short* qb = (unsigned short*)W;      W += CY*2;                       // q
  unsigned short* kb = (unsigned short*)W;      W += CY*2;                       // k
  unsigned short* vt = (unsigned short*)W;      W += (size_t)DIMS_*RMAXP*2;      // v^T or v row-major
  unsigned short* ab = (unsigned short*)W;      W += CY*2;
  unsigned short* wt_attn = (unsigned short*)W; W += (size_t)24*160*160*2;
  unsigned short* wt_w1   = (unsigned short*)W; W += (size_t)6*320*160*2;
  unsigned short* wt_w2   = (unsigned short*)W; W += (size_t)6*160*320*2;
  float* nsoft = (float*)W;                     W += (size_t)NNODES*32*4;
  int* patch_ids = (int*)W;
  int* pk     = patch_ids + NNODES;
  int* cnt    = pk + NNODES;
  int* offs   = cnt + 8;
  int* cntmax = offs + 8;

  // deterministic padding rows
  hipMemsetAsync(pf, 0, (size_t)(RMAX2 + 16)*DIMS_*4, stream);

  cvt_all<<<dim3(100, 36), 256, 0, stream>>>(attn_W, mlp_W1, mlp_W2, wt_attn, wt_w1, wt_w2);

  patch_kernel<<<(NNODES + 127)/128, 128, 0, stream>>>(node_tab, patch_emb, probs_st, nsoft, patch_ids);
  scan_kernel<<<1, 1024, 0, stream>>>(patch_ids, pk, cnt, offs, cntmax);
  embed_kernel<<<dim3(NNODES, BB), 160, 0, stream>>>(x, te, conv_W, conv_b, tod_emb, dow_emb, nsoft, pk, pf);

  const int GX = RMAX2 / 16;   // 472 row tiles

  // first xn = LN0(pf)
  ln_xn<<<GX, 64, 0, stream>>>(pf, ln_scale, ln_bias, xn);

  for (int l = 0; l < 3; ++l) {
    for (int a = 0; a < 2; ++a) {
      int wb = l*2 + a;
      const float* bbase = attn_b + (size_t)wb*4*DIMS_;
      const unsigned short* wqkv = wt_attn + (size_t)wb*4*25600;
      const float* g1  = ln_scale + (size_t)(l*4 + a*2 + 1)*DIMS_;
      const float* bt1 = ln_bias  + (size_t)(l*4 + a*2 + 1)*DIMS_;
      bool hasnext = !(l == 2 && a == 1);
      int nidx = (a == 0) ? (l*4 + 2) : ((l+1)*4);
      const float* gn  = hasnext ? ln_scale + (size_t)nidx*DIMS_ : nullptr;
      const float* btn = hasnext ? ln_bias  + (size_t)nidx*DIMS_ : nullptr;

      // QKV from xn (bf16): q,k row-major; V transposed (intra) or row-major (inter)
      if (a == 0)
        mfma_mm<160,true,5><<<dim3(GX,2,3), 64, 0, stream>>>(
            xn, wqkv, bbase, qb, RMAX2, DIMS_, 25600, CY, DIMS_);
      else
        mfma_mm<160,false,5><<<dim3(GX,2,3), 64, 0, stream>>>(
            xn, wqkv, bbase, qb, RMAX2, DIMS_, 25600, CY, DIMS_);

      if (a == 0)
        intra_attn_mfma<<<dim3(16, 8, BB), 64, 0, stream>>>(qb, kb, vt, ab, cnt, offs);
      else
        inter_attn<<<dim3(NNODES, BB), 64, 0, stream>>>(qb, kb, vt, ab, cnt, offs, cntmax);

      // fused proj + residual + LN + MLP1 + MLP2 + residual + LN_next (4-wave col-split)
      const unsigned short* wproj = wqkv + 3*25600;
      const float* bproj = bbase + 3*DIMS_;
      const unsigned short* w1 = wt_w1 + (size_t)wb*51200;
      const unsigned short* w2 = wt_w2 + (size_t)wb*51200;
      const float* b1v = mlp_b1 + (size_t)wb*HID_;
      const float* b2v = mlp_b2 + (size_t)wb*DIMS_;
      if (hasnext)
        fused_mlp<true><<<GX, 256, 0, stream>>>(ab, wproj, bproj, w1, b1v, w2, b2v,
                                                g1, bt1, gn, btn, pf, xn);
      else
        fused_mlp<false><<<GX, 256, 0, stream>>>(ab, wproj, bproj, w1, b1v, w2, b2v,
                                                 g1, bt1, nullptr, nullptr, pf, xn);
    }
  }

  out_kernel<<<(BB*12*NNODES + 255)/256, 256, 0, stream>>>(pf, out_W, out_b, pk, out);
}